// Round 2
// baseline (183.462 us; speedup 1.0000x reference)
//
#include <hip/hip_runtime.h>
#include <hip/hip_bf16.h>
#include <math.h>

// Problem constants (SimpleMemoryBank: B=8,T=4096,D=512,SLOTS=128,TOPK=8)
#define R_TOTAL 32768   // B*T rows
#define DM      512
#define NSLOT   128
#define KSEL    8
#define MTILE   32
#define KTILE   32

__global__ __launch_bounds__(256, 4) void smb_fused(
    const float* __restrict__ q,    // [R_TOTAL, DM]
    const float* __restrict__ Km,   // [NSLOT, DM]
    const float* __restrict__ Vm,   // [NSLOT, DM]
    const float* __restrict__ sal,  // [NSLOT]
    float* __restrict__ outv,       // [R_TOTAL, DM]
    float* __restrict__ outw)       // [R_TOTAL, KSEL]
{
  // LDS: GEMM tiles and the scores buffer are live in disjoint phases -> union.
  __shared__ union U {
    struct { float As[32][36]; float Bs[32][132]; } ab;  // padded strides
    float scores[32][132];
  } u;
  __shared__ float wbuf[32][KSEL];
  __shared__ int   ibuf[32][KSEL];

  const int t  = threadIdx.x;
  const int r0 = blockIdx.x * MTILE;

  // ---------------- Phase A: scores = q @ K^T (fp32, d-ascending accumulation) -------------
  const int sy    = t >> 5;        // row group 0..7 (4 rows each)
  const int tx    = t & 31;        // slot group (4 slots each)
  const int row_a = t >> 3;        // staging: q row this thread loads (0..31)
  const int dca   = (t & 7) << 2;  // staging: float4 column offset

  float sal4[4];
#pragma unroll
  for (int j = 0; j < 4; ++j) sal4[j] = sal[tx * 4 + j];

  float acc[4][4];
#pragma unroll
  for (int i = 0; i < 4; ++i)
#pragma unroll
    for (int j = 0; j < 4; ++j) acc[i][j] = 0.0f;

  for (int dc = 0; dc < DM; dc += KTILE) {
    // global loads for this chunk (issued before the barrier; no LDS touched yet)
    const float4 av = *(const float4*)(q + (size_t)(r0 + row_a) * DM + dc + dca);
    float4 bv[4];
#pragma unroll
    for (int it = 0; it < 4; ++it) {
      const int uu  = t + it * 256;
      const int s_  = uu >> 3;          // slot 0..127
      const int dcb = (uu & 7) << 2;    // d offset 0..28
      bv[it] = *(const float4*)(Km + (size_t)s_ * DM + dc + dcb);
    }
    __syncthreads();  // previous chunk's compute done reading LDS
    *(float4*)&u.ab.As[row_a][dca] = av;
#pragma unroll
    for (int it = 0; it < 4; ++it) {
      const int uu  = t + it * 256;
      const int s_  = uu >> 3;
      const int dcb = (uu & 7) << 2;
      u.ab.Bs[dcb + 0][s_] = bv[it].x;   // transpose K tile into [d][slot]
      u.ab.Bs[dcb + 1][s_] = bv[it].y;
      u.ab.Bs[dcb + 2][s_] = bv[it].z;
      u.ab.Bs[dcb + 3][s_] = bv[it].w;
    }
    __syncthreads();
#pragma unroll
    for (int d4 = 0; d4 < KTILE; d4 += 4) {
      float a_[4][4], b_[4][4];
#pragma unroll
      for (int i = 0; i < 4; ++i) {
        const float4 v = *(const float4*)&u.ab.As[sy * 4 + i][d4];  // broadcast read
        a_[i][0] = v.x; a_[i][1] = v.y; a_[i][2] = v.z; a_[i][3] = v.w;
      }
#pragma unroll
      for (int dd = 0; dd < 4; ++dd) {
        const float4 v = *(const float4*)&u.ab.Bs[d4 + dd][tx * 4];
        b_[dd][0] = v.x; b_[dd][1] = v.y; b_[dd][2] = v.z; b_[dd][3] = v.w;
      }
      // dd outermost => each acc[i][j] accumulates with d strictly ascending (np-like order)
#pragma unroll
      for (int dd = 0; dd < 4; ++dd)
#pragma unroll
        for (int i = 0; i < 4; ++i)
#pragma unroll
          for (int j = 0; j < 4; ++j)
            acc[i][j] = fmaf(a_[i][dd], b_[dd][j], acc[i][j]);
    }
  }
  __syncthreads();  // done with As/Bs; scores aliases them

  const float den = sqrtf((float)DM);  // IEEE fp32 division below matches np's "/"
#pragma unroll
  for (int i = 0; i < 4; ++i) {
    float4 sc;
    sc.x = acc[i][0] / den + sal4[0];
    sc.y = acc[i][1] / den + sal4[1];
    sc.z = acc[i][2] / den + sal4[2];
    sc.w = acc[i][3] / den + sal4[3];
    *(float4*)&u.scores[sy * 4 + i][tx * 4] = sc;
  }
  __syncthreads();

  // ---------------- Phase B: per-row top-8 (jax.lax.top_k tie semantics) + softmax ---------
  // 8 lanes per row; lane l scans j = 8*jj + l (ascending j within each lane).
  const int row = t >> 3;  // 0..31
  const int l   = t & 7;

  float bs[8]; int bi[8];
#pragma unroll
  for (int p = 0; p < 8; ++p) { bs[p] = -3.0e38f; bi[p] = 0x7fffffff; }

#pragma unroll
  for (int jj = 0; jj < 16; ++jj) {
    const int   j = jj * 8 + l;
    const float s = u.scores[row][j];
    bool c[8];
#pragma unroll
    for (int p = 0; p < 8; ++p) c[p] = s > bs[p];   // strict: equal scores keep earlier index
    float nb[8]; int ni[8];
    nb[0] = c[0] ? s : bs[0];
    ni[0] = c[0] ? j : bi[0];
#pragma unroll
    for (int p = 7; p >= 1; --p) {
      nb[p] = c[p] ? (c[p - 1] ? bs[p - 1] : s) : bs[p];
      ni[p] = c[p] ? (c[p - 1] ? bi[p - 1] : j) : bi[p];
    }
#pragma unroll
    for (int p = 0; p < 8; ++p) { bs[p] = nb[p]; bi[p] = ni[p]; }
  }

  // merge the 8 lanes' sorted lists: 8 rounds of oct-max (score desc, index asc) + pop
  float ts[8]; int ti_[8];
#pragma unroll
  for (int r = 0; r < 8; ++r) {
    float hs = bs[0]; int hi = bi[0];
#pragma unroll
    for (int m = 1; m <= 4; m <<= 1) {
      const float os = __shfl_xor(hs, m, 64);
      const int   oi = __shfl_xor(hi, m, 64);
      if (os > hs || (os == hs && oi < hi)) { hs = os; hi = oi; }
    }
    ts[r] = hs; ti_[r] = hi;
    if (bs[0] == hs && bi[0] == hi) {  // winner lane pops its head (static shift)
#pragma unroll
      for (int p = 0; p < 7; ++p) { bs[p] = bs[p + 1]; bi[p] = bi[p + 1]; }
      bs[7] = -3.0e38f; bi[7] = 0x7fffffff;
    }
  }

  // softmax over the 8 selected scores (exp(x - max) / sum), all oct lanes redundantly
  float tw[8];
  const float mx = ts[0];
  float esum = 0.0f;
#pragma unroll
  for (int r = 0; r < 8; ++r) { tw[r] = expf(ts[r] - mx); esum += tw[r]; }
#pragma unroll
  for (int r = 0; r < 8; ++r) tw[r] /= esum;

  if (l == 0) {
#pragma unroll
    for (int r = 0; r < 8; ++r) {
      wbuf[row][r] = tw[r];
      ibuf[row][r] = ti_[r];
      outw[(size_t)(r0 + row) * KSEL + r] = tw[r];
    }
  }
  __syncthreads();

  // ---------------- Phase C: read_vectors = sum_k w_k * V[idx_k] ---------------------------
  // 8 lanes per row; lane o covers float4 columns c = cc*8 + o (128B-coalesced per oct).
  const int o  = t & 7;
  const int rr = t >> 3;  // 0..31
  const float4* __restrict__ V4 = (const float4*)Vm;
  float4* __restrict__ O4 = (float4*)outv;
  float w8[8]; int i8[8];
#pragma unroll
  for (int r = 0; r < 8; ++r) { w8[r] = wbuf[rr][r]; i8[r] = ibuf[rr][r]; }
  const size_t obase = (size_t)(r0 + rr) * (DM / 4);
#pragma unroll
  for (int cc = 0; cc < 16; ++cc) {
    const int c = cc * 8 + o;
    float4 a; a.x = a.y = a.z = a.w = 0.0f;
#pragma unroll
    for (int r = 0; r < 8; ++r) {  // k ascending, matches reference einsum order
      const float4 v = V4[(size_t)i8[r] * (DM / 4) + c];
      a.x = fmaf(w8[r], v.x, a.x);
      a.y = fmaf(w8[r], v.y, a.y);
      a.z = fmaf(w8[r], v.z, a.z);
      a.w = fmaf(w8[r], v.w, a.w);
    }
    O4[obase + c] = a;
  }
}

extern "C" void kernel_launch(void* const* d_in, const int* in_sizes, int n_in,
                              void* d_out, int out_size, void* d_ws, size_t ws_size,
                              hipStream_t stream) {
  const float* q   = (const float*)d_in[0];
  const float* Km  = (const float*)d_in[1];
  const float* Vm  = (const float*)d_in[2];
  const float* sal = (const float*)d_in[3];
  // d_in[4] is topk (scalar int) — fixed at 8 for this problem.
  float* outv = (float*)d_out;
  float* outw = outv + (size_t)R_TOTAL * DM;  // outputs concatenated flat in return order

  dim3 grid(R_TOTAL / MTILE);
  dim3 block(256);
  hipLaunchKernelGGL(smb_fused, grid, block, 0, stream, q, Km, Vm, sal, outv, outw);
}

// Round 3
// 104.777 us; speedup vs baseline: 1.7510x; 1.7510x over previous
//
#include <hip/hip_runtime.h>
#include <hip/hip_bf16.h>
#include <math.h>

// SimpleMemoryBank: B=8,T=4096,D=512,SLOTS=128,TOPK=8
#define R_TOTAL 32768
#define DM      512
#define NSLOT   128
#define KSEL    8

typedef _Float16 half8 __attribute__((ext_vector_type(8)));
typedef float    floatx4 __attribute__((ext_vector_type(4)));

// ---------------- prep: split K into f16 hi/lo (scaled by 256 so residuals are normal f16) ---
__global__ void smb_splitK(const float* __restrict__ Km,
                           _Float16* __restrict__ K1, _Float16* __restrict__ K2) {
  const int i = blockIdx.x * 256 + threadIdx.x;      // grid covers NSLOT*DM = 65536
  const float f = Km[i] * 256.0f;                    // exact (power of 2)
  const _Float16 h = (_Float16)f;
  K1[i] = h;
  K2[i] = (_Float16)(f - (float)h);                  // f - (float)h exact (Sterbenz)
}

// ---------------- fused main: per-wave 16 rows, no barriers anywhere ------------------------
__global__ __launch_bounds__(256, 2) void smb_main(
    const float* __restrict__ q,     // [R_TOTAL, DM]
    const _Float16* __restrict__ K1, // [NSLOT, DM] hi
    const _Float16* __restrict__ K2, // [NSLOT, DM] lo
    const float* __restrict__ Vm,    // [NSLOT, DM]
    const float* __restrict__ sal,   // [NSLOT]
    float* __restrict__ outv,        // [R_TOTAL, DM]
    float* __restrict__ outw)        // [R_TOTAL, KSEL]
{
  __shared__ float slab[4][16][132];   // per-wave score slab (2-way banks at stride 132)

  const int t  = threadIdx.x;
  const int w  = t >> 6;          // wave 0..3
  const int l  = t & 63;          // lane
  const int li = l & 15;          // M-row / B-col within fragment
  const int kg = l >> 4;          // k-group 0..3 (k = kg*8 + j)
  const int r0w = blockIdx.x * 64 + w * 16;   // this wave's 16 q rows

  // ---- Phase A0: issue ALL q loads for this lane (16 chunks x 32B) up front ----
  // lane covers q[r0w+li][c*32 + kg*8 .. +7] for c=0..15
  float4 qv[32];
  const float* qrow = q + (size_t)(r0w + li) * DM + kg * 8;
#pragma unroll
  for (int c = 0; c < 16; ++c) {
    qv[2 * c]     = *(const float4*)(qrow + c * 32);
    qv[2 * c + 1] = *(const float4*)(qrow + c * 32 + 4);
  }

  floatx4 acc[8];
#pragma unroll
  for (int g = 0; g < 8; ++g) acc[g] = (floatx4){0.f, 0.f, 0.f, 0.f};

  // B fragment base: lane reads K[(g*16+li)][c*32 + kg*8 .. +7]  (16B contiguous, L2-hot)
  const _Float16* k1p = K1 + (size_t)li * DM + kg * 8;
  const _Float16* k2p = K2 + (size_t)li * DM + kg * 8;

  // ---- Phase A1: scores via f16-split MFMA: (16q)(256K) = 4096*qK, 3 terms ----
#pragma unroll
  for (int c = 0; c < 16; ++c) {
    half8 a1, a2;
#pragma unroll
    for (int j = 0; j < 4; ++j) {
      const float f0 = qv[2 * c][j] * 16.0f;       // exact scale
      const float f1 = qv[2 * c + 1][j] * 16.0f;
      const _Float16 h0 = (_Float16)f0;
      const _Float16 h1 = (_Float16)f1;
      a1[j]     = h0;  a2[j]     = (_Float16)(f0 - (float)h0);
      a1[4 + j] = h1;  a2[4 + j] = (_Float16)(f1 - (float)h1);
    }
#pragma unroll
    for (int g = 0; g < 8; ++g) {
      const half8 b1 = *(const half8*)(k1p + g * 16 * DM + c * 32);
      const half8 b2 = *(const half8*)(k2p + g * 16 * DM + c * 32);
      acc[g] = __builtin_amdgcn_mfma_f32_16x16x32_f16(a1, b1, acc[g], 0, 0, 0);
      acc[g] = __builtin_amdgcn_mfma_f32_16x16x32_f16(a2, b1, acc[g], 0, 0, 0);
      acc[g] = __builtin_amdgcn_mfma_f32_16x16x32_f16(a1, b2, acc[g], 0, 0, 0);
    }
  }

  // ---- epilogue: scores = (acc/4096)/sqrt(D) + salience; dump to per-wave slab ----
  // D-frag layout (m89-verified): col = lane&15, row = (lane>>4)*4 + reg
  const float den = sqrtf((float)DM);
#pragma unroll
  for (int g = 0; g < 8; ++g) {
    const float sv = sal[g * 16 + li];
#pragma unroll
    for (int i = 0; i < 4; ++i) {
      const float s = (acc[g][i] * 0.000244140625f) / den + sv;  // *2^-12 exact, IEEE div
      slab[w][kg * 4 + i][g * 16 + li] = s;
    }
  }
  asm volatile("s_waitcnt lgkmcnt(0)" ::: "memory");   // same-wave LDS write->read fence

  // ---- Phase B: per-row top-8 (tie: lower index) + softmax. 4 lanes/row, R0-proven. ----
  const int row = l >> 2;   // 0..15
  const int lq  = l & 3;

  float bs[8]; int bi[8];
#pragma unroll
  for (int p = 0; p < 8; ++p) { bs[p] = -3.0e38f; bi[p] = 0x7fffffff; }

#pragma unroll
  for (int jj = 0; jj < 32; ++jj) {
    const int   j = jj * 4 + lq;
    const float s = slab[w][row][j];
    bool c[8];
#pragma unroll
    for (int p = 0; p < 8; ++p) c[p] = s > bs[p];   // strict > keeps earlier index on ties
    float nb[8]; int ni[8];
    nb[0] = c[0] ? s : bs[0];
    ni[0] = c[0] ? j : bi[0];
#pragma unroll
    for (int p = 7; p >= 1; --p) {
      nb[p] = c[p] ? (c[p - 1] ? bs[p - 1] : s) : bs[p];
      ni[p] = c[p] ? (c[p - 1] ? bi[p - 1] : j) : bi[p];
    }
#pragma unroll
    for (int p = 0; p < 8; ++p) { bs[p] = nb[p]; bi[p] = ni[p]; }
  }

  // merge 4 sorted lists via quad butterflies (score desc, index asc) + pop
  float ts[8]; int ti_[8];
#pragma unroll
  for (int r = 0; r < 8; ++r) {
    float hs = bs[0]; int hi = bi[0];
    {
      const float os = __shfl_xor(hs, 1, 64);
      const int   oi = __shfl_xor(hi, 1, 64);
      if (os > hs || (os == hs && oi < hi)) { hs = os; hi = oi; }
    }
    {
      const float os = __shfl_xor(hs, 2, 64);
      const int   oi = __shfl_xor(hi, 2, 64);
      if (os > hs || (os == hs && oi < hi)) { hs = os; hi = oi; }
    }
    ts[r] = hs; ti_[r] = hi;
    if (bs[0] == hs && bi[0] == hi) {
#pragma unroll
      for (int p = 0; p < 7; ++p) { bs[p] = bs[p + 1]; bi[p] = bi[p + 1]; }
      bs[7] = -3.0e38f; bi[7] = 0x7fffffff;
    }
  }

  float tw[8];
  const float mx = ts[0];
  float esum = 0.0f;
#pragma unroll
  for (int r = 0; r < 8; ++r) { tw[r] = expf(ts[r] - mx); esum += tw[r]; }
#pragma unroll
  for (int r = 0; r < 8; ++r) tw[r] /= esum;

  if (lq == 0) {
#pragma unroll
    for (int r = 0; r < 8; ++r) outw[(size_t)(r0w + row) * KSEL + r] = tw[r];
  }

  // ---- Phase C: read_vectors = sum_k w_k * V[idx_k]; quad-local (w,i in regs) ----
  const float4* __restrict__ V4 = (const float4*)Vm;
  float4* __restrict__ O4 = (float4*)outv;
  const size_t obase = (size_t)(r0w + row) * (DM / 4);
#pragma unroll 4
  for (int cc = 0; cc < 32; ++cc) {
    const int cdx = cc * 4 + lq;
    float4 a; a.x = a.y = a.z = a.w = 0.0f;
#pragma unroll
    for (int r = 0; r < 8; ++r) {   // k ascending, matches reference einsum order
      const float4 v = V4[(size_t)ti_[r] * (DM / 4) + cdx];
      a.x = fmaf(tw[r], v.x, a.x);
      a.y = fmaf(tw[r], v.y, a.y);
      a.z = fmaf(tw[r], v.z, a.z);
      a.w = fmaf(tw[r], v.w, a.w);
    }
    O4[obase + cdx] = a;
  }
}

extern "C" void kernel_launch(void* const* d_in, const int* in_sizes, int n_in,
                              void* d_out, int out_size, void* d_ws, size_t ws_size,
                              hipStream_t stream) {
  const float* q   = (const float*)d_in[0];
  const float* Km  = (const float*)d_in[1];
  const float* Vm  = (const float*)d_in[2];
  const float* sal = (const float*)d_in[3];
  // d_in[4] = topk (fixed 8)

  float* outv = (float*)d_out;
  float* outw = outv + (size_t)R_TOTAL * DM;

  _Float16* K1 = (_Float16*)d_ws;                 // 128 KB
  _Float16* K2 = K1 + (size_t)NSLOT * DM;         // 128 KB

  hipLaunchKernelGGL(smb_splitK, dim3((NSLOT * DM) / 256), dim3(256), 0, stream, Km, K1, K2);
  hipLaunchKernelGGL(smb_main, dim3(R_TOTAL / 64), dim3(256), 0, stream,
                     q, K1, K2, Vm, sal, outv, outw);
}